// Round 1
// 124.359 us; speedup vs baseline: 1.0028x; 1.0028x over previous
//
#include <hip/hip_runtime.h>
#include <cmath>

#define DIM 128
#define NHALF 4096
#define NROWS 8192
// FRAG_SCALE^2 = log2(e)/tau = 1.4426950408889634/0.5
#define FRAG_SCALE 1.69864368f

typedef __attribute__((ext_vector_type(8))) short bf16x8;
typedef __attribute__((ext_vector_type(4))) float f32x4;

static __device__ __forceinline__ unsigned short f32_to_bf16(float f) {
  unsigned int u = __float_as_uint(f);
  u = (u + 0x7FFFu + ((u >> 16) & 1u)) >> 16;
  return (unsigned short)u;
}

// One wave per pair r in [0,4096): L2-normalize z_i[r], z_j[r], scale by
// sqrt(log2e/tau), store bf16 rows r and r+4096; pos[r]=pos[r+4096] =
// dot(zi,zj)/(|zi||zj|)/tau computed in fp32. Also zeroes out[0] (finalize
// accumulates into it with one atomic per block).
__global__ __launch_bounds__(256) void prep_kernel(
    const float* __restrict__ z_i, const float* __restrict__ z_j,
    unsigned short* __restrict__ A, float* __restrict__ pos,
    float* __restrict__ out) {
  int wave = threadIdx.x >> 6;
  int lane = threadIdx.x & 63;
  int r = blockIdx.x * 4 + wave;
  if (blockIdx.x == 0 && threadIdx.x == 0) out[0] = 0.0f;
  float2 a = *(const float2*)(z_i + (size_t)r * DIM + 2 * lane);
  float2 b = *(const float2*)(z_j + (size_t)r * DIM + 2 * lane);
  float sa = a.x * a.x + a.y * a.y;
  float sb = b.x * b.x + b.y * b.y;
  float dp = a.x * b.x + a.y * b.y;
#pragma unroll
  for (int off = 1; off < 64; off <<= 1) {
    sa += __shfl_xor(sa, off);
    sb += __shfl_xor(sb, off);
    dp += __shfl_xor(dp, off);
  }
  float na = fmaxf(sqrtf(sa), 1e-8f);
  float nb = fmaxf(sqrtf(sb), 1e-8f);
  float si = FRAG_SCALE / na;
  float sj = FRAG_SCALE / nb;
  unsigned int pa = (unsigned int)f32_to_bf16(a.x * si) |
                    ((unsigned int)f32_to_bf16(a.y * si) << 16);
  unsigned int pb = (unsigned int)f32_to_bf16(b.x * sj) |
                    ((unsigned int)f32_to_bf16(b.y * sj) << 16);
  ((unsigned int*)A)[(size_t)r * (DIM / 2) + lane] = pa;
  ((unsigned int*)A)[(size_t)(r + NHALF) * (DIM / 2) + lane] = pb;
  if (lane == 0) {
    float p = dp / (na * nb) * 2.0f;  // /tau, tau=0.5
    pos[r] = p;
    pos[r + NHALF] = p;
  }
}

// Upper-triangle tiles only (sim is symmetric): 2080 workgroups, each a
// 128x128 tile. LDS-free main loop: MFMA fragments loaded directly from
// global (A is 2 MB, L2-resident). Epilogue: per-block LDS reduction of
// row/col exp-sums, then ONE coalesced store per row/col partial into a
// disjoint slot of partials[64][8192] — zero global atomics.
// Slot map: tile (bi,bj): row-side -> slot (bj-bi), col-side -> slot
// (64-bj+bi). For every row-block b this fills slots 0..63 exactly once.
__global__ __launch_bounds__(256) void simexp_kernel(
    const unsigned short* __restrict__ A, float* __restrict__ partials) {
  const int tid = threadIdx.x;
  const int lane = tid & 63;
  const int w = tid >> 6;
  const int q = lane >> 4;
  const int n = lane & 15;

  __shared__ float redR[128];
  __shared__ float redC[128];
  if (tid < 128) redR[tid] = 0.0f;
  else redC[tid - 128] = 0.0f;

  // decode upper-triangle tile index t -> (bi, bj), bi <= bj, 64 blocks
  int t = blockIdx.x;
  int bi = (int)((129.0f - sqrtf(16641.0f - 8.0f * (float)t)) * 0.5f);
  int start = 64 * bi - (bi * (bi - 1)) / 2;
  if (t < start) {
    bi--;
    start = 64 * bi - (bi * (bi - 1)) / 2;
  } else if (t >= start + (64 - bi)) {
    start += 64 - bi;
    bi++;
  }
  int bj = bi + (t - start);

  const int rbBase = bi * 128;
  const int cbBase = bj * 128;
  const int wrow = (w & 1) * 64;
  const int wcol = (w >> 1) * 64;
  const bool diag = (bi == bj);

  const unsigned short* Arow = A + (size_t)(rbBase + wrow) * DIM;
  const unsigned short* Brow = A + (size_t)(cbBase + wcol) * DIM;

  f32x4 acc[16];
#pragma unroll
  for (int i = 0; i < 16; i++)
#pragma unroll
    for (int j = 0; j < 4; j++) acc[i][j] = 0.0f;

#pragma unroll
  for (int kc = 0; kc < 4; kc++) {
    bf16x8 af[4], bfr[4];
#pragma unroll
    for (int mi = 0; mi < 4; mi++)
      af[mi] = *(const bf16x8*)(Arow + (mi * 16 + n) * DIM + kc * 32 + q * 8);
#pragma unroll
    for (int ni = 0; ni < 4; ni++)
      bfr[ni] = *(const bf16x8*)(Brow + (ni * 16 + n) * DIM + kc * 32 + q * 8);
#pragma unroll
    for (int mi = 0; mi < 4; mi++)
#pragma unroll
      for (int ni = 0; ni < 4; ni++)
        acc[mi * 4 + ni] = __builtin_amdgcn_mfma_f32_16x16x32_bf16(
            af[mi], bfr[ni], acc[mi * 4 + ni], 0, 0, 0);
  }

  // epilogue: exp2, diagonal mask, row + column accumulation (registers)
  float eaccR[16];
  float eaccC[4];
#pragma unroll
  for (int i = 0; i < 16; i++) eaccR[i] = 0.0f;
#pragma unroll
  for (int i = 0; i < 4; i++) eaccC[i] = 0.0f;
#pragma unroll
  for (int mi = 0; mi < 4; mi++) {
#pragma unroll
    for (int ni = 0; ni < 4; ni++) {
#pragma unroll
      for (int rg = 0; rg < 4; rg++) {
        float v = acc[mi * 4 + ni][rg];
        float e = __builtin_amdgcn_exp2f(v);
        int grow = rbBase + wrow + mi * 16 + q * 4 + rg;
        int gcol = cbBase + wcol + ni * 16 + n;
        e = (grow == gcol) ? 0.0f : e;
        eaccR[mi * 4 + rg] += e;
        eaccC[ni] += e;
      }
    }
  }

  // make sure LDS zero-init is visible before any LDS atomic
  __syncthreads();

  // row sums: reduce across n (16 lanes per q-group) -> LDS (cross-wave)
#pragma unroll
  for (int mi = 0; mi < 4; mi++) {
#pragma unroll
    for (int rg = 0; rg < 4; rg++) {
      float v = eaccR[mi * 4 + rg];
      v += __shfl_xor(v, 1);
      v += __shfl_xor(v, 2);
      v += __shfl_xor(v, 4);
      v += __shfl_xor(v, 8);
      if (n == 0)
        atomicAdd(&redR[wrow + mi * 16 + q * 4 + rg], v);
    }
  }
  // column sums (symmetry credit): reduce across q -> LDS (cross-wave)
#pragma unroll
  for (int ni = 0; ni < 4; ni++) {
    float v = eaccC[ni];
    v += __shfl_xor(v, 16);
    v += __shfl_xor(v, 32);
    if (lane < 16) atomicAdd(&redC[wcol + ni * 16 + n], v);
  }
  __syncthreads();

  // coalesced partial stores: 128 row-partials + 128 col-partials per tile
  if (tid < 128) {
    partials[(size_t)(bj - bi) * NROWS + rbBase + tid] = redR[tid];
  } else if (!diag) {
    partials[(size_t)(64 - bj + bi) * NROWS + cbBase + (tid - 128)] =
        redC[tid - 128];
  }
}

// loss = mean over rows of log(rowsum) - pos; rowsum = sum of the row's 64
// partial slots. 32 blocks x 256 threads, one row per thread; per-k loads
// are coalesced across the block. One atomicAdd on out[0] per block.
__global__ __launch_bounds__(256) void finalize_kernel(
    const float* __restrict__ partials, const float* __restrict__ pos,
    float* __restrict__ out) {
  int tid = threadIdx.x;
  int r = blockIdx.x * 256 + tid;
  float s = 0.0f;
#pragma unroll
  for (int k = 0; k < 64; k++) s += partials[(size_t)k * NROWS + r];
  float local = logf(s) - pos[r];
#pragma unroll
  for (int off = 1; off < 64; off <<= 1) local += __shfl_xor(local, off);
  __shared__ float wsum[4];
  if ((tid & 63) == 0) wsum[tid >> 6] = local;
  __syncthreads();
  if (tid == 0)
    atomicAdd(out, (wsum[0] + wsum[1] + wsum[2] + wsum[3]) *
                       (1.0f / (float)NROWS));
}

extern "C" void kernel_launch(void* const* d_in, const int* in_sizes, int n_in,
                              void* d_out, int out_size, void* d_ws,
                              size_t ws_size, hipStream_t stream) {
  const float* z_i = (const float*)d_in[0];
  const float* z_j = (const float*)d_in[1];
  float* out = (float*)d_out;

  unsigned short* A = (unsigned short*)d_ws;               // 8192*128 bf16 = 2 MB
  float* partials = (float*)((char*)d_ws + (1u << 21));    // 64*8192 f32 = 2 MB
  float* pos = (float*)((char*)d_ws + (2u << 21));         // 32 KB

  prep_kernel<<<NHALF / 4, 256, 0, stream>>>(z_i, z_j, A, pos, out);
  simexp_kernel<<<2080, 256, 0, stream>>>(A, partials);
  finalize_kernel<<<32, 256, 0, stream>>>(partials, pos, out);
}

// Round 2
// 109.929 us; speedup vs baseline: 1.1345x; 1.1313x over previous
//
#include <hip/hip_runtime.h>
#include <cmath>

#define DIM 128
#define NHALF 4096
#define NROWS 8192
// FRAG_SCALE^2 = log2(e)/tau = 1.4426950408889634/0.5
#define FRAG_SCALE 1.69864368f

typedef __attribute__((ext_vector_type(8))) short bf16x8;
typedef __attribute__((ext_vector_type(4))) float f32x4;

static __device__ __forceinline__ unsigned short f32_to_bf16(float f) {
  unsigned int u = __float_as_uint(f);
  u = (u + 0x7FFFu + ((u >> 16) & 1u)) >> 16;
  return (unsigned short)u;
}

// async global->LDS, 16 B per lane; lds base must be wave-uniform.
static __device__ __forceinline__ void gload_lds16(const void* g, void* l) {
  __builtin_amdgcn_global_load_lds(
      (const __attribute__((address_space(1))) unsigned int*)g,
      (__attribute__((address_space(3))) unsigned int*)l, 16, 0, 0);
}

// One wave per pair r in [0,4096): L2-normalize z_i[r], z_j[r], scale by
// sqrt(log2e/tau), store bf16 rows r and r+4096; pos[r]=pos[r+4096] =
// dot(zi,zj)/(|zi||zj|)/tau computed in fp32. Also zeroes out[0].
__global__ __launch_bounds__(256) void prep_kernel(
    const float* __restrict__ z_i, const float* __restrict__ z_j,
    unsigned short* __restrict__ A, float* __restrict__ pos,
    float* __restrict__ out) {
  int wave = threadIdx.x >> 6;
  int lane = threadIdx.x & 63;
  int r = blockIdx.x * 4 + wave;
  if (blockIdx.x == 0 && threadIdx.x == 0) out[0] = 0.0f;
  float2 a = *(const float2*)(z_i + (size_t)r * DIM + 2 * lane);
  float2 b = *(const float2*)(z_j + (size_t)r * DIM + 2 * lane);
  float sa = a.x * a.x + a.y * a.y;
  float sb = b.x * b.x + b.y * b.y;
  float dp = a.x * b.x + a.y * b.y;
#pragma unroll
  for (int off = 1; off < 64; off <<= 1) {
    sa += __shfl_xor(sa, off);
    sb += __shfl_xor(sb, off);
    dp += __shfl_xor(dp, off);
  }
  float na = fmaxf(sqrtf(sa), 1e-8f);
  float nb = fmaxf(sqrtf(sb), 1e-8f);
  float si = FRAG_SCALE / na;
  float sj = FRAG_SCALE / nb;
  unsigned int pa = (unsigned int)f32_to_bf16(a.x * si) |
                    ((unsigned int)f32_to_bf16(a.y * si) << 16);
  unsigned int pb = (unsigned int)f32_to_bf16(b.x * sj) |
                    ((unsigned int)f32_to_bf16(b.y * sj) << 16);
  ((unsigned int*)A)[(size_t)r * (DIM / 2) + lane] = pa;
  ((unsigned int*)A)[(size_t)(r + NHALF) * (DIM / 2) + lane] = pb;
  if (lane == 0) {
    float p = dp / (na * nb) * 2.0f;  // /tau, tau=0.5
    pos[r] = p;
    pos[r + NHALF] = p;
  }
}

// Upper-triangle tiles only (sim is symmetric): 2080 workgroups, each a
// 128x128 tile. A-panel and B-panel (32 KB each, contiguous rows of A) are
// staged into LDS via global_load_lds width=16 (one bulk async copy), with a
// per-row XOR swizzle applied on the GLOBAL source (rule: linear LDS dest +
// inverse-swz source + swz read) so ds_read_b128 is bank-conflict-free.
// Epilogue: LDS reduction of row/col exp-sums, disjoint-slot partial stores
// into partials[64][8192] — zero global atomics.
__global__ __launch_bounds__(256) void simexp_kernel(
    const unsigned short* __restrict__ A, float* __restrict__ partials) {
  const int tid = threadIdx.x;
  const int lane = tid & 63;
  const int w = tid >> 6;
  const int q = lane >> 4;
  const int n = lane & 15;

  __shared__ alignas(16) unsigned short As[128 * DIM];  // 32 KB
  __shared__ alignas(16) unsigned short Bs[128 * DIM];  // 32 KB
  __shared__ float redR[128];
  __shared__ float redC[128];
  if (tid < 128) redR[tid] = 0.0f;
  else redC[tid - 128] = 0.0f;

  // decode upper-triangle tile index t -> (bi, bj), bi <= bj, 64 blocks
  int t = blockIdx.x;
  int bi = (int)((129.0f - sqrtf(16641.0f - 8.0f * (float)t)) * 0.5f);
  int start = 64 * bi - (bi * (bi - 1)) / 2;
  if (t < start) {
    bi--;
    start = 64 * bi - (bi * (bi - 1)) / 2;
  } else if (t >= start + (64 - bi)) {
    start += 64 - bi;
    bi++;
  }
  int bj = bi + (t - start);

  const int rbBase = bi * 128;
  const int cbBase = bj * 128;
  const int wrow = (w & 1) * 64;
  const int wcol = (w >> 1) * 64;
  const bool diag = (bi == bj);

  // ---- stage panels: 16 global_load_lds_dwordx4 per thread-position ----
  // chunk = i*4 + w covers rows [chunk*4, chunk*4+4); lane covers
  // row = chunk*4 + (lane>>4), 16B-group (lane&15). Source group is
  // XOR-swizzled by (row&7); LDS dest stays linear (HW: base + lane*16).
  {
    const unsigned short* gA = A + (size_t)rbBase * DIM;
    const unsigned short* gB = A + (size_t)cbBase * DIM;
    const int c = lane & 15;
    const int rsub = lane >> 4;
#pragma unroll
    for (int i = 0; i < 8; i++) {
      int chunk = i * 4 + w;
      int row = chunk * 4 + rsub;
      int srcoff = row * DIM + ((c ^ (row & 7)) << 3);  // ushort elements
      gload_lds16(gA + srcoff, (char*)As + chunk * 1024);
      gload_lds16(gB + srcoff, (char*)Bs + chunk * 1024);
    }
  }
  __syncthreads();  // drains vmcnt(0) before barrier -> panels + red* ready

  // ---- MFMA main loop, fragments from LDS (swizzled read) ----
  f32x4 acc[16];
#pragma unroll
  for (int i = 0; i < 16; i++)
#pragma unroll
    for (int j = 0; j < 4; j++) acc[i][j] = 0.0f;

#pragma unroll
  for (int kc = 0; kc < 4; kc++) {
    bf16x8 af[4], bfr[4];
    const int cg = kc * 4 + q;  // 16B column-group index 0..15
#pragma unroll
    for (int mi = 0; mi < 4; mi++) {
      int row = wrow + mi * 16 + n;
      af[mi] = *(const bf16x8*)(As + row * DIM + ((cg ^ (row & 7)) << 3));
    }
#pragma unroll
    for (int ni = 0; ni < 4; ni++) {
      int row = wcol + ni * 16 + n;
      bfr[ni] = *(const bf16x8*)(Bs + row * DIM + ((cg ^ (row & 7)) << 3));
    }
#pragma unroll
    for (int mi = 0; mi < 4; mi++)
#pragma unroll
      for (int ni = 0; ni < 4; ni++)
        acc[mi * 4 + ni] = __builtin_amdgcn_mfma_f32_16x16x32_bf16(
            af[mi], bfr[ni], acc[mi * 4 + ni], 0, 0, 0);
  }

  // epilogue: exp2, diagonal mask, row + column accumulation (registers)
  float eaccR[16];
  float eaccC[4];
#pragma unroll
  for (int i = 0; i < 16; i++) eaccR[i] = 0.0f;
#pragma unroll
  for (int i = 0; i < 4; i++) eaccC[i] = 0.0f;
#pragma unroll
  for (int mi = 0; mi < 4; mi++) {
#pragma unroll
    for (int ni = 0; ni < 4; ni++) {
#pragma unroll
      for (int rg = 0; rg < 4; rg++) {
        float v = acc[mi * 4 + ni][rg];
        float e = __builtin_amdgcn_exp2f(v);
        int grow = rbBase + wrow + mi * 16 + q * 4 + rg;
        int gcol = cbBase + wcol + ni * 16 + n;
        e = (grow == gcol) ? 0.0f : e;
        eaccR[mi * 4 + rg] += e;
        eaccC[ni] += e;
      }
    }
  }

  // row sums: reduce across n (16 lanes per q-group) -> LDS (cross-wave)
#pragma unroll
  for (int mi = 0; mi < 4; mi++) {
#pragma unroll
    for (int rg = 0; rg < 4; rg++) {
      float v = eaccR[mi * 4 + rg];
      v += __shfl_xor(v, 1);
      v += __shfl_xor(v, 2);
      v += __shfl_xor(v, 4);
      v += __shfl_xor(v, 8);
      if (n == 0)
        atomicAdd(&redR[wrow + mi * 16 + q * 4 + rg], v);
    }
  }
  // column sums (symmetry credit): reduce across q -> LDS (cross-wave)
#pragma unroll
  for (int ni = 0; ni < 4; ni++) {
    float v = eaccC[ni];
    v += __shfl_xor(v, 16);
    v += __shfl_xor(v, 32);
    if (lane < 16) atomicAdd(&redC[wcol + ni * 16 + n], v);
  }
  __syncthreads();

  // coalesced partial stores: 128 row-partials + 128 col-partials per tile.
  // Slot map: row-side -> slot (bj-bi), col-side -> slot (64-bj+bi); every
  // row-block gets slots 0..63 filled exactly once.
  if (tid < 128) {
    partials[(size_t)(bj - bi) * NROWS + rbBase + tid] = redR[tid];
  } else if (!diag) {
    partials[(size_t)(64 - bj + bi) * NROWS + cbBase + (tid - 128)] =
        redC[tid - 128];
  }
}

// loss = mean over rows of log(rowsum) - pos; rowsum = sum of the row's 64
// partial slots. 32 blocks x 256 threads, one row per thread; per-k loads
// are coalesced across the block. One atomicAdd on out[0] per block.
__global__ __launch_bounds__(256) void finalize_kernel(
    const float* __restrict__ partials, const float* __restrict__ pos,
    float* __restrict__ out) {
  int tid = threadIdx.x;
  int r = blockIdx.x * 256 + tid;
  float s = 0.0f;
#pragma unroll
  for (int k = 0; k < 64; k++) s += partials[(size_t)k * NROWS + r];
  float local = logf(s) - pos[r];
#pragma unroll
  for (int off = 1; off < 64; off <<= 1) local += __shfl_xor(local, off);
  __shared__ float wsum[4];
  if ((tid & 63) == 0) wsum[tid >> 6] = local;
  __syncthreads();
  if (tid == 0)
    atomicAdd(out, (wsum[0] + wsum[1] + wsum[2] + wsum[3]) *
                       (1.0f / (float)NROWS));
}

extern "C" void kernel_launch(void* const* d_in, const int* in_sizes, int n_in,
                              void* d_out, int out_size, void* d_ws,
                              size_t ws_size, hipStream_t stream) {
  const float* z_i = (const float*)d_in[0];
  const float* z_j = (const float*)d_in[1];
  float* out = (float*)d_out;

  unsigned short* A = (unsigned short*)d_ws;               // 8192*128 bf16 = 2 MB
  float* partials = (float*)((char*)d_ws + (1u << 21));    // 64*8192 f32 = 2 MB
  float* pos = (float*)((char*)d_ws + (2u << 21));         // 32 KB

  prep_kernel<<<NHALF / 4, 256, 0, stream>>>(z_i, z_j, A, pos, out);
  simexp_kernel<<<2080, 256, 0, stream>>>(A, partials);
  finalize_kernel<<<32, 256, 0, stream>>>(partials, pos, out);
}